// Round 4
// baseline (412.437 us; speedup 1.0000x reference)
//
#include <hip/hip_runtime.h>
#include <stdint.h>

#define M_ROWS 16384   // B*S
#define N_COLS 4096    // OUT
#define K_DIM  1024    // IN
#define NT     (K_DIM / 128)   // 8 K-tiles of BK=128 (int8)

typedef int   i32x4 __attribute__((ext_vector_type(4)));

// ---- async global->LDS, 16B per lane, LDS dest is wave-uniform base + lane*16
__device__ __forceinline__ void gload_lds16(const void* g, void* l) {
    __builtin_amdgcn_global_load_lds(
        (const __attribute__((address_space(1))) unsigned int*)g,
        (__attribute__((address_space(3))) unsigned int*)l, 16, 0, 0);
}

// ---------------- kernel 1: per-block min/max of x ----------------
__global__ void k_minmax(const float4* __restrict__ x,
                         float* __restrict__ pmax, float* __restrict__ pmin) {
    const int n4 = (M_ROWS * K_DIM) / 4;
    float mx = -3.402823466e38f, mn = 3.402823466e38f;
    for (int i = blockIdx.x * blockDim.x + threadIdx.x; i < n4;
         i += gridDim.x * blockDim.x) {
        float4 v = x[i];
        mx = fmaxf(mx, fmaxf(fmaxf(v.x, v.y), fmaxf(v.z, v.w)));
        mn = fminf(mn, fminf(fminf(v.x, v.y), fminf(v.z, v.w)));
    }
#pragma unroll
    for (int off = 32; off > 0; off >>= 1) {
        mx = fmaxf(mx, __shfl_xor(mx, off));
        mn = fminf(mn, __shfl_xor(mn, off));
    }
    __shared__ float smx[4], smn[4];
    const int wave = threadIdx.x >> 6, lane = threadIdx.x & 63;
    if (lane == 0) { smx[wave] = mx; smn[wave] = mn; }
    __syncthreads();
    if (threadIdx.x == 0) {
        mx = fmaxf(fmaxf(smx[0], smx[1]), fmaxf(smx[2], smx[3]));
        mn = fminf(fminf(smn[0], smn[1]), fminf(smn[2], smn[3]));
        pmax[blockIdx.x] = mx;
        pmin[blockIdx.x] = mn;
    }
}

// ---------------- kernel 2: final scalars (scale, zp, alpha) ----------------
__global__ void k_scalars(const float* __restrict__ pmax, const float* __restrict__ pmin,
                          const float* __restrict__ w_scale, float* __restrict__ scal) {
    float mx = -3.402823466e38f, mn = 3.402823466e38f;
    for (int i = threadIdx.x; i < 2048; i += 256) {
        mx = fmaxf(mx, pmax[i]);
        mn = fminf(mn, pmin[i]);
    }
#pragma unroll
    for (int off = 32; off > 0; off >>= 1) {
        mx = fmaxf(mx, __shfl_xor(mx, off));
        mn = fminf(mn, __shfl_xor(mn, off));
    }
    __shared__ float smx[4], smn[4];
    const int wave = threadIdx.x >> 6, lane = threadIdx.x & 63;
    if (lane == 0) { smx[wave] = mx; smn[wave] = mn; }
    __syncthreads();
    if (threadIdx.x == 0) {
        mx = fmaxf(fmaxf(smx[0], smx[1]), fmaxf(smx[2], smx[3]));
        mn = fminf(fminf(smn[0], smn[1]), fminf(smn[2], smn[3]));
        const float scale = (mx - mn) / 255.0f;
        const float zp = rintf((mx * -128.0f - mn * 127.0f) / (mx - mn));
        scal[0] = scale;
        scal[1] = zp;
        scal[2] = scale * w_scale[0];
    }
}

// ------- kernel 3: quantize x -> int8 + row term (cm[m] = zw*(K*zx - sx[m]))
__global__ void k_quant(const float* __restrict__ x, const float* __restrict__ scal,
                        const float* __restrict__ wzp,
                        int4* __restrict__ xc8, float* __restrict__ cm) {
    const float scale = scal[0], zx = scal[1], zw = wzp[0];
    const int lane = threadIdx.x & 63;
    const int gw = (blockIdx.x * blockDim.x + threadIdx.x) >> 6;
    const int nw = (gridDim.x * blockDim.x) >> 6;
    for (int row = gw; row < M_ROWS; row += nw) {
        const float4* xr = (const float4*)(x + (size_t)row * K_DIM + lane * 16);
        union { signed char c[16]; int4 v; } u;
        int s = 0;
#pragma unroll
        for (int e = 0; e < 4; ++e) {
            float4 v = xr[e];
            signed char c0 = (signed char)(int)(rintf(v.x / scale) + zx);
            signed char c1 = (signed char)(int)(rintf(v.y / scale) + zx);
            signed char c2 = (signed char)(int)(rintf(v.z / scale) + zx);
            signed char c3 = (signed char)(int)(rintf(v.w / scale) + zx);
            u.c[e * 4 + 0] = c0; u.c[e * 4 + 1] = c1;
            u.c[e * 4 + 2] = c2; u.c[e * 4 + 3] = c3;
            s += (int)c0 + (int)c1 + (int)c2 + (int)c3;
        }
        xc8[row * 64 + lane] = u.v;
#pragma unroll
        for (int off = 32; off > 0; off >>= 1) s += __shfl_xor(s, off);
        if (lane == 0) cm[row] = zw * (1024.0f * zx - (float)s);
    }
}

// ------- kernel 4: pack weights -> int8 + row term (cn[o] = -zx*sw[o]) ------
__global__ void k_prepw(const int* __restrict__ wq, const float* __restrict__ scal,
                        int4* __restrict__ wc8, float* __restrict__ cn) {
    const float zx = scal[1];
    const int lane = threadIdx.x & 63;
    const int gw = (blockIdx.x * blockDim.x + threadIdx.x) >> 6;
    const int nw = (gridDim.x * blockDim.x) >> 6;
    for (int row = gw; row < N_COLS; row += nw) {
        const int4* wr = (const int4*)(wq + (size_t)row * K_DIM + lane * 16);
        union { signed char c[16]; int4 v; } u;
        int s = 0;
#pragma unroll
        for (int e = 0; e < 4; ++e) {
            int4 v = wr[e];
            u.c[e * 4 + 0] = (signed char)v.x;
            u.c[e * 4 + 1] = (signed char)v.y;
            u.c[e * 4 + 2] = (signed char)v.z;
            u.c[e * 4 + 3] = (signed char)v.w;
            s += v.x + v.y + v.z + v.w;
        }
        wc8[row * 64 + lane] = u.v;
#pragma unroll
        for (int off = 32; off > 0; off >>= 1) s += __shfl_xor(s, off);
        if (lane == 0) cn[row] = -zx * (float)s;
    }
}

// ---------------- kernel 5: 128x128x128 int8 GEMM, m97 2-phase structure -----
// out[m,o] = (i32dot(x_q[m,:],w_q[o,:]) + cm[m] + cn[o]) * alpha + bias[o]
// 256 thr = 4 waves (2M x 2N), per-wave 64x64 out (acc 4x4 of 16x16 frags).
// LDS 32 KiB single-buffer -> ~3 blocks/CU resident (VGPR-capped): one block's
// staging drain / epilogue overlaps neighbors' MFMA (m114 mechanism).
// Same XOR swizzle as before: phys_byte = logical ^ ((row&7)<<4), rows = 128B.
__global__ __launch_bounds__(256, 3)
void k_gemm(const signed char* __restrict__ A,
            const signed char* __restrict__ B,
            const float* __restrict__ scal,
            const float* __restrict__ bias,
            const float* __restrict__ cm,
            const float* __restrict__ cn,
            float* __restrict__ C) {
    __shared__ char lds[32768];   // A tile at 0 (16KB), B tile at 16384

    const int tid  = threadIdx.x;
    const int wave = tid >> 6, lane = tid & 63;
    const int wm = wave >> 1, wn = wave & 1;     // 2 x 2 wave grid
    const int fr = lane & 15, kg = lane >> 4;

    // XCD-aware bijective swizzle: nwg = 4096 = 8 * 512
    const int wg  = blockIdx.x;
    const int swz = ((wg & 7) << 9) | (wg >> 3);
    const int bm  = swz >> 5;    // 0..127  (M tiles)
    const int bn  = swz & 31;    // 0..31   (N tiles; bn-fastest -> A-tile L2 reuse)

    // staging lane geometry (pre-swizzled global source); rows are 1024 B
    const int scol = ((tid & 7) ^ ((tid >> 3) & 7)) << 4;
    const char* gA = (const char*)A + (size_t)(bm * 128 + (tid >> 3)) * K_DIM + scol;
    const char* gB = (const char*)B + (size_t)(bn * 128 + (tid >> 3)) * K_DIM + scol;

    // fragment-read constants (swizzled); kk selects 64-byte K-half
    const int kx0 = ((kg * 16) ^ ((fr & 7) << 4));
    const int kx1 = ((64 + kg * 16) ^ ((fr & 7) << 4));
    const int arow = (wm * 64 + fr) * 128;   // byte base in A tile
    const int brow = (wn * 64 + fr) * 128;   // byte base in B tile

    i32x4 acc[4][4] = {};

    for (int t = 0; t < NT; ++t) {
        // ---- stage tile t: 4 calls A + 4 calls B (each 256 lanes x 16B = 4KB)
#pragma unroll
        for (int h = 0; h < 4; ++h) {
            const size_t goff = (size_t)t * 128 + (size_t)h * 32 * 1024;
            gload_lds16(gA + goff, lds + h * 4096 + wave * 1024);
            gload_lds16(gB + goff, lds + 16384 + h * 4096 + wave * 1024);
        }
        __syncthreads();   // compiler emits vmcnt(0)+lgkmcnt(0) drain before s_barrier

        i32x4 af[4][2], bf[4][2];
#pragma unroll
        for (int i = 0; i < 4; ++i) {
            af[i][0] = *(const i32x4*)(lds + arow + i * 2048 + kx0);
            af[i][1] = *(const i32x4*)(lds + arow + i * 2048 + kx1);
            bf[i][0] = *(const i32x4*)(lds + 16384 + brow + i * 2048 + kx0);
            bf[i][1] = *(const i32x4*)(lds + 16384 + brow + i * 2048 + kx1);
        }
#pragma unroll
        for (int kk = 0; kk < 2; ++kk)
#pragma unroll
            for (int i = 0; i < 4; ++i)
#pragma unroll
                for (int j = 0; j < 4; ++j)
                    acc[i][j] = __builtin_amdgcn_mfma_i32_16x16x64_i8(
                        af[i][kk], bf[j][kk], acc[i][j], 0, 0, 0);
        __syncthreads();   // protect LDS before next tile's overwrite
    }

    // ---- epilogue: C/D layout col=lane&15, row=(lane>>4)*4+r ----
    const float alpha = scal[2];
    const int gc_base = bn * 128 + wn * 64;
    const int gr_base = bm * 128 + wm * 64;
    float bb[4], cc[4];
#pragma unroll
    for (int j = 0; j < 4; ++j) {
        const int gc = gc_base + j * 16 + fr;
        bb[j] = bias[gc];
        cc[j] = cn[gc];
    }
#pragma unroll
    for (int i = 0; i < 4; ++i) {
        const int gr0 = gr_base + i * 16 + kg * 4;
        const float4 cmv = *(const float4*)(cm + gr0);
#pragma unroll
        for (int j = 0; j < 4; ++j) {
            const int gc = gc_base + j * 16 + fr;
            C[(size_t)(gr0 + 0) * N_COLS + gc] = ((float)acc[i][j][0] + cmv.x + cc[j]) * alpha + bb[j];
            C[(size_t)(gr0 + 1) * N_COLS + gc] = ((float)acc[i][j][1] + cmv.y + cc[j]) * alpha + bb[j];
            C[(size_t)(gr0 + 2) * N_COLS + gc] = ((float)acc[i][j][2] + cmv.z + cc[j]) * alpha + bb[j];
            C[(size_t)(gr0 + 3) * N_COLS + gc] = ((float)acc[i][j][3] + cmv.w + cc[j]) * alpha + bb[j];
        }
    }
}

extern "C" void kernel_launch(void* const* d_in, const int* in_sizes, int n_in,
                              void* d_out, int out_size, void* d_ws, size_t ws_size,
                              hipStream_t stream) {
    const float* x    = (const float*)d_in[0];   // [8,2048,1024] f32
    const int*   wq   = (const int*)d_in[1];     // [4096,1024] int32 (int8 values)
    const float* wsc  = (const float*)d_in[2];   // scalar
    const float* wzp  = (const float*)d_in[3];   // scalar
    const float* bias = (const float*)d_in[4];   // [4096]
    float* out = (float*)d_out;                  // [8,2048,4096] f32

    char* ws = (char*)d_ws;
    int4*  xc8  = (int4*)(ws);                   // 16,777,216 B
    int4*  wc8  = (int4*)(ws + 16777216);        //  4,194,304 B
    float* cm   = (float*)(ws + 20971520);       //  65,536 B
    float* cn   = (float*)(ws + 21037056);       //  16,384 B
    float* pmax = (float*)(ws + 21053440);
    float* pmin = (float*)(ws + 21061632);
    float* scal = (float*)(ws + 21069824);

    k_minmax <<<2048, 256, 0, stream>>>((const float4*)x, pmax, pmin);
    k_scalars<<<1,    256, 0, stream>>>(pmax, pmin, wsc, scal);
    k_prepw  <<<1024, 256, 0, stream>>>(wq, scal, wc8, cn);
    k_quant  <<<2048, 256, 0, stream>>>(x, scal, wzp, xc8, cm);
    k_gemm   <<<4096, 256, 0, stream>>>((const signed char*)xc8, (const signed char*)wc8,
                                        scal, bias, cm, cn, out);
}